// Round 2
// baseline (1363.311 us; speedup 1.0000x reference)
//
#include <hip/hip_runtime.h>
#include <stdint.h>

// Linear4Bit: out[8192,4096] = x[8192,4096] @ W^T + bias, W = dequant(int4 codes, group-16 fp32 scales)
// Strategy: bf16 split-precision GEMM (3 cross terms) on MFMA.
//   x = x_hi + x_lo (bf16 each), W = W_hi + W_lo (bf16 each)
//   y = x_hi@W_hi + x_hi@W_lo + x_lo@W_hi   (x_lo@W_lo ~ 2^-16 rel, dropped)
// Workspace layout (needs 192 MiB):
//   Ahi [8192*4096] ushort | Alo [8192*4096] | Bhi [4096*4096] | Blo [4096*4096]

#define TOKENS 8192
#define INF    4096
#define OUTF   4096
#define GROUPS (INF / 16)   // 256
#define PACKED (INF / 2)    // 2048

typedef short bf16x8 __attribute__((ext_vector_type(8)));
typedef float f32x4 __attribute__((ext_vector_type(4)));

// bf16 round-to-nearest-even via bit ops (no API ambiguity)
__device__ __forceinline__ unsigned short f2bf(float f) {
    uint32_t u = __float_as_uint(f);
    u += 0x7fffu + ((u >> 16) & 1u);
    return (unsigned short)(u >> 16);
}
__device__ __forceinline__ float bf2f(unsigned short h) {
    return __uint_as_float(((uint32_t)h) << 16);
}

// ---------------- prep: x -> (x_hi, x_lo) bf16 ----------------
__global__ __launch_bounds__(256) void prep_x_kernel(
    const float4* __restrict__ x, ushort4* __restrict__ ahi, ushort4* __restrict__ alo) {
    int i = blockIdx.x * 256 + threadIdx.x;   // grid sized exactly: TOKENS*INF/4 threads
    float4 v = x[i];
    ushort4 h, l;
    h.x = f2bf(v.x); l.x = f2bf(v.x - bf2f(h.x));
    h.y = f2bf(v.y); l.y = f2bf(v.y - bf2f(h.y));
    h.z = f2bf(v.z); l.z = f2bf(v.z - bf2f(h.z));
    h.w = f2bf(v.w); l.w = f2bf(v.w - bf2f(h.w));
    ahi[i] = h; alo[i] = l;
}

// ---------------- prep: dequant W -> (W_hi, W_lo) bf16 ----------------
__device__ __forceinline__ float dq(int q, float s) {
    // exactly the reference arithmetic: s * (2*(q/15) - 1), fp32
    return s * (2.0f * ((float)q / 15.0f) - 1.0f);
}

__global__ __launch_bounds__(256) void prep_w_kernel(
    const int4* __restrict__ wq, const float* __restrict__ wn,
    ushort4* __restrict__ bhi, ushort4* __restrict__ blo) {
    int i = blockIdx.x * 256 + threadIdx.x;        // one int4 = 4 packed bytes = 8 codes
    int n  = i / (PACKED / 4);                     // output row
    int p4 = i - n * (PACKED / 4);                 // int4 index within row
    // unpacked k = p4*8 .. p4*8+7; group = k/16 = p4/2 (uniform across the 8 codes)
    float s = wn[n * GROUPS + (p4 >> 1)];
    int4 v = wq[i];
    float w[8];
    w[0] = dq(v.x & 15, s);        w[1] = dq((v.x >> 4) & 15, s);
    w[2] = dq(v.y & 15, s);        w[3] = dq((v.y >> 4) & 15, s);
    w[4] = dq(v.z & 15, s);        w[5] = dq((v.z >> 4) & 15, s);
    w[6] = dq(v.w & 15, s);        w[7] = dq((v.w >> 4) & 15, s);
    ushort4 h0, h1, l0, l1;
    h0.x = f2bf(w[0]); l0.x = f2bf(w[0] - bf2f(h0.x));
    h0.y = f2bf(w[1]); l0.y = f2bf(w[1] - bf2f(h0.y));
    h0.z = f2bf(w[2]); l0.z = f2bf(w[2] - bf2f(h0.z));
    h0.w = f2bf(w[3]); l0.w = f2bf(w[3] - bf2f(h0.w));
    h1.x = f2bf(w[4]); l1.x = f2bf(w[4] - bf2f(h1.x));
    h1.y = f2bf(w[5]); l1.y = f2bf(w[5] - bf2f(h1.y));
    h1.z = f2bf(w[6]); l1.z = f2bf(w[6] - bf2f(h1.z));
    h1.w = f2bf(w[7]); l1.w = f2bf(w[7] - bf2f(h1.w));
    bhi[i * 2] = h0; bhi[i * 2 + 1] = h1;
    blo[i * 2] = l0; blo[i * 2 + 1] = l1;
}

// ---------------- 3-term split GEMM, 128x128 tile, BK=32 ----------------
#define GLDS(g, l) __builtin_amdgcn_global_load_lds(                         \
    (const __attribute__((address_space(1))) void*)(g),                      \
    (__attribute__((address_space(3))) void*)(l), 16, 0, 0)

__global__ __launch_bounds__(256, 2) void gemm3_kernel(
    const unsigned short* __restrict__ Ahi, const unsigned short* __restrict__ Alo,
    const unsigned short* __restrict__ Bhi, const unsigned short* __restrict__ Blo,
    const float* __restrict__ bias, float* __restrict__ C) {
    // 4 tiles of [128][32] ushort (8 KB each) = 32 KB LDS, single-buffered (m97 2-barrier)
    __shared__ unsigned short lds[4 * 128 * 32];

    const int NB_N = OUTF / 128;                    // 32
    const int nwg  = (TOKENS / 128) * NB_N;         // 2048 (divisible by 8 -> simple swizzle bijective)
    int bid = blockIdx.x;
    int swz = (bid & 7) * (nwg >> 3) + (bid >> 3);  // XCD-aware swizzle
    int tm = swz / NB_N, tn = swz % NB_N;
    int brow = tm * 128, bcol = tn * 128;

    int tid = threadIdx.x;
    int lane = tid & 63, wave = tid >> 6;
    int wr = wave >> 1, wc = wave & 1;              // wave owns 64x64 at (wr*64, wc*64)

    unsigned short* lAh = lds;
    unsigned short* lAl = lds + 4096;
    unsigned short* lBh = lds + 8192;
    unsigned short* lBl = lds + 12288;

    // staging: thread t loads row (t>>2), cols (t&3)*8 .. +8 (16B), twice per tile (rows +64)
    int sr = tid >> 2, sc = (tid & 3) * 8;
    const unsigned short* gAh = Ahi + (size_t)(brow + sr) * INF + sc;
    const unsigned short* gAl = Alo + (size_t)(brow + sr) * INF + sc;
    const unsigned short* gBh = Bhi + (size_t)(bcol + sr) * INF + sc;
    const unsigned short* gBl = Blo + (size_t)(bcol + sr) * INF + sc;
    unsigned short* sdst = lds + tid * 8;           // tid*16 bytes: linear in thread order (gload_lds reqt)

    f32x4 acc[4][4] = {};

    int ar = wr * 64 + (lane & 15);                 // A fragment row within tile
    int br = wc * 64 + (lane & 15);                 // B fragment row (N-major W layout)
    int kf = (lane >> 4) * 8;                       // K-chunk per lane group

    for (int k0 = 0; k0 < INF; k0 += 32) {
        GLDS(gAh + k0,            sdst);
        GLDS(gAh + k0 + 64 * INF, sdst + 2048);
        GLDS(gAl + k0,            sdst + 4096);
        GLDS(gAl + k0 + 64 * INF, sdst + 6144);
        GLDS(gBh + k0,            sdst + 8192);
        GLDS(gBh + k0 + 64 * INF, sdst + 10240);
        GLDS(gBl + k0,            sdst + 12288);
        GLDS(gBl + k0 + 64 * INF, sdst + 14336);
        __syncthreads();   // compiler emits vmcnt(0) drain before barrier

        bf16x8 ah[4], al[4], bh[4], bl[4];
#pragma unroll
        for (int mi = 0; mi < 4; ++mi) {
            ah[mi] = *(const bf16x8*)&lAh[(ar + mi * 16) * 32 + kf];
            al[mi] = *(const bf16x8*)&lAl[(ar + mi * 16) * 32 + kf];
        }
#pragma unroll
        for (int ni = 0; ni < 4; ++ni) {
            bh[ni] = *(const bf16x8*)&lBh[(br + ni * 16) * 32 + kf];
            bl[ni] = *(const bf16x8*)&lBl[(br + ni * 16) * 32 + kf];
        }
#pragma unroll
        for (int mi = 0; mi < 4; ++mi)
#pragma unroll
            for (int ni = 0; ni < 4; ++ni) {
                acc[mi][ni] = __builtin_amdgcn_mfma_f32_16x16x32_bf16(ah[mi], bh[ni], acc[mi][ni], 0, 0, 0);
                acc[mi][ni] = __builtin_amdgcn_mfma_f32_16x16x32_bf16(ah[mi], bl[ni], acc[mi][ni], 0, 0, 0);
                acc[mi][ni] = __builtin_amdgcn_mfma_f32_16x16x32_bf16(al[mi], bh[ni], acc[mi][ni], 0, 0, 0);
            }
        __syncthreads();
    }

    // epilogue: C/D layout col=lane&15, row=(lane>>4)*4+reg (m89/m91-verified)
    int ccol = bcol + wc * 64 + (lane & 15);
    int crow = brow + wr * 64 + (lane >> 4) * 4;
    float bv[4];
#pragma unroll
    for (int ni = 0; ni < 4; ++ni) bv[ni] = bias[ccol + ni * 16];
#pragma unroll
    for (int mi = 0; mi < 4; ++mi) {
#pragma unroll
        for (int j = 0; j < 4; ++j) {
            float* cp = C + (size_t)(crow + mi * 16 + j) * OUTF + ccol;
#pragma unroll
            for (int ni = 0; ni < 4; ++ni)
                cp[ni * 16] = acc[mi][ni][j] + bv[ni];
        }
    }
}

extern "C" void kernel_launch(void* const* d_in, const int* in_sizes, int n_in,
                              void* d_out, int out_size, void* d_ws, size_t ws_size,
                              hipStream_t stream) {
    const float* x    = (const float*)d_in[0];
    const int*   wq   = (const int*)d_in[1];
    const float* wn   = (const float*)d_in[2];
    const float* bias = (const float*)d_in[3];
    float* out = (float*)d_out;

    // workspace: Ahi|Alo|Bhi|Blo  (192 MiB total)
    unsigned short* Ahi = (unsigned short*)d_ws;
    unsigned short* Alo = Ahi + (size_t)TOKENS * INF;
    unsigned short* Bhi = Alo + (size_t)TOKENS * INF;
    unsigned short* Blo = Bhi + (size_t)OUTF * INF;

    prep_x_kernel<<<(TOKENS * INF / 4) / 256, 256, 0, stream>>>(
        (const float4*)x, (ushort4*)Ahi, (ushort4*)Alo);
    prep_w_kernel<<<(OUTF * PACKED / 4) / 256, 256, 0, stream>>>(
        (const int4*)wq, wn, (ushort4*)Bhi, (ushort4*)Blo);
    gemm3_kernel<<<2048, 256, 0, stream>>>(Ahi, Alo, Bhi, Blo, bias, out);
}

// Round 3
// 1362.154 us; speedup vs baseline: 1.0008x; 1.0008x over previous
//
#include <hip/hip_runtime.h>
#include <stdint.h>

// Linear4Bit: out[8192,4096] = x @ W^T + bias, W = dequant(int4, group-16 fp32 scales)
// bf16 3-term split GEMM as K-concat pipeline:
//   steps per k0: (x_hi,W_hi), (x_hi,W_lo), (x_lo,W_hi)  -> 384 uniform steps
// Ring of 3 LDS buffers, stage-ahead-2, counted vmcnt(4) (never 0 in loop),
// one raw s_barrier per step, both-sides XOR swizzle slot^=(row>>1)&3.

#define TOKENS 8192
#define INF    4096
#define OUTF   4096
#define GROUPS (INF / 16)   // 256
#define PACKED (INF / 2)    // 2048

typedef short bf16x8 __attribute__((ext_vector_type(8)));
typedef float f32x4 __attribute__((ext_vector_type(4)));

__device__ __forceinline__ unsigned short f2bf(float f) {
    uint32_t u = __float_as_uint(f);
    u += 0x7fffu + ((u >> 16) & 1u);
    return (unsigned short)(u >> 16);
}
__device__ __forceinline__ float bf2f(unsigned short h) {
    return __uint_as_float(((uint32_t)h) << 16);
}

// ---------------- prep: x -> (x_hi, x_lo) bf16 ----------------
__global__ __launch_bounds__(256) void prep_x_kernel(
    const float4* __restrict__ x, ushort4* __restrict__ ahi, ushort4* __restrict__ alo) {
    int i = blockIdx.x * 256 + threadIdx.x;
    float4 v = x[i];
    ushort4 h, l;
    h.x = f2bf(v.x); l.x = f2bf(v.x - bf2f(h.x));
    h.y = f2bf(v.y); l.y = f2bf(v.y - bf2f(h.y));
    h.z = f2bf(v.z); l.z = f2bf(v.z - bf2f(h.z));
    h.w = f2bf(v.w); l.w = f2bf(v.w - bf2f(h.w));
    ahi[i] = h; alo[i] = l;
}

// ---------------- prep: dequant W -> (W_hi, W_lo) bf16 ----------------
__device__ __forceinline__ float dq(int q, float s) {
    return s * (2.0f * ((float)q / 15.0f) - 1.0f);
}

__global__ __launch_bounds__(256) void prep_w_kernel(
    const int4* __restrict__ wq, const float* __restrict__ wn,
    ushort4* __restrict__ bhi, ushort4* __restrict__ blo) {
    int i = blockIdx.x * 256 + threadIdx.x;        // one int4 = 4 int32 "bytes" = 8 codes
    int n  = i / (PACKED / 4);
    int p4 = i - n * (PACKED / 4);
    float s = wn[n * GROUPS + (p4 >> 1)];
    int4 v = wq[i];
    float w[8];
    w[0] = dq(v.x & 15, s);        w[1] = dq((v.x >> 4) & 15, s);
    w[2] = dq(v.y & 15, s);        w[3] = dq((v.y >> 4) & 15, s);
    w[4] = dq(v.z & 15, s);        w[5] = dq((v.z >> 4) & 15, s);
    w[6] = dq(v.w & 15, s);        w[7] = dq((v.w >> 4) & 15, s);
    ushort4 h0, h1, l0, l1;
    h0.x = f2bf(w[0]); l0.x = f2bf(w[0] - bf2f(h0.x));
    h0.y = f2bf(w[1]); l0.y = f2bf(w[1] - bf2f(h0.y));
    h0.z = f2bf(w[2]); l0.z = f2bf(w[2] - bf2f(h0.z));
    h0.w = f2bf(w[3]); l0.w = f2bf(w[3] - bf2f(h0.w));
    h1.x = f2bf(w[4]); l1.x = f2bf(w[4] - bf2f(h1.x));
    h1.y = f2bf(w[5]); l1.y = f2bf(w[5] - bf2f(h1.y));
    h1.z = f2bf(w[6]); l1.z = f2bf(w[6] - bf2f(h1.z));
    h1.w = f2bf(w[7]); l1.w = f2bf(w[7] - bf2f(h1.w));
    bhi[i * 2] = h0; bhi[i * 2 + 1] = h1;
    blo[i * 2] = l0; blo[i * 2 + 1] = l1;
}

// ---------------- pipelined 3-term GEMM ----------------
#define GLDS(g, l) __builtin_amdgcn_global_load_lds(                         \
    (const __attribute__((address_space(1))) void*)(g),                      \
    (__attribute__((address_space(3))) void*)(l), 16, 0, 0)

#define WAIT4 { asm volatile("s_waitcnt vmcnt(4)" ::: "memory"); \
                __builtin_amdgcn_sched_barrier(0); }
#define WAIT0 { asm volatile("s_waitcnt vmcnt(0)" ::: "memory"); \
                __builtin_amdgcn_sched_barrier(0); }
#define BAR   { __builtin_amdgcn_s_barrier(); \
                __builtin_amdgcn_sched_barrier(0); }

__global__ __launch_bounds__(256, 3) void gemm3_kernel(
    const unsigned short* __restrict__ Ahi, const unsigned short* __restrict__ Alo,
    const unsigned short* __restrict__ Bhi, const unsigned short* __restrict__ Blo,
    const float* __restrict__ bias, float* __restrict__ C) {
    // 3 ring buffers of (A[128][32] + B[128][32]) bf16 = 16 KB each -> 48 KB
    __shared__ unsigned short lds[3 * 8192];

    const int NB_N = OUTF / 128;                    // 32
    const int nwg  = (TOKENS / 128) * NB_N;         // 2048 (% 8 == 0 -> bijective swizzle)
    int bid = blockIdx.x;
    int swz = (bid & 7) * (nwg >> 3) + (bid >> 3);
    int tm = swz / NB_N, tn = swz % NB_N;
    int brow = tm * 128, bcol = tn * 128;

    int tid = threadIdx.x;
    int lane = tid & 63, wave = tid >> 6;
    int wr = wave >> 1, wc = wave & 1;              // wave: 64x64 sub-tile

    // ---- staging addresses (pre-swizzled global source, linear LDS dest) ----
    int srow = tid >> 2;                            // 0..63
    int sslot = (tid & 3) ^ ((srow >> 1) & 3);      // XOR swizzle, row+64 invariant
    size_t offA0 = (size_t)(brow + srow) * INF + sslot * 8;
    size_t offB0 = (size_t)(bcol + srow) * INF + sslot * 8;
    const size_t off64 = (size_t)64 * INF;

#define ISSUE(bi, As, Bs, kk) {                                   \
    GLDS((As) + offA0 + (kk),         lds + (bi)*8192 + tid*8);   \
    GLDS((As) + offA0 + off64 + (kk), lds + (bi)*8192 + 2048 + tid*8); \
    GLDS((Bs) + offB0 + (kk),         lds + (bi)*8192 + 4096 + tid*8); \
    GLDS((Bs) + offB0 + off64 + (kk), lds + (bi)*8192 + 6144 + tid*8); }

    // ---- fragment read addresses (swizzled) ----
    int rbase = wr * 64 + (lane & 15);
    int cbase = wc * 64 + (lane & 15);
    int kf = (lane >> 4) * 8;                       // 16B slot per lane-group
    int xa = kf ^ (((rbase >> 1) & 3) << 3);        // mi*16 doesn't change (r>>1)&3
    int xb = kf ^ (((cbase >> 1) & 3) << 3);

    f32x4 acc[4][4] = {};

#define COMPUTE(bi) {                                                        \
    const unsigned short* bA = lds + (bi)*8192;                              \
    const unsigned short* bB = bA + 4096;                                    \
    bf16x8 af[4], bfr[4];                                                    \
    _Pragma("unroll") for (int mi = 0; mi < 4; ++mi)                         \
        af[mi] = *(const bf16x8*)&bA[(rbase + mi*16)*32 + xa];               \
    _Pragma("unroll") for (int ni = 0; ni < 4; ++ni)                         \
        bfr[ni] = *(const bf16x8*)&bB[(cbase + ni*16)*32 + xb];              \
    _Pragma("unroll") for (int mi = 0; mi < 4; ++mi)                         \
    _Pragma("unroll") for (int ni = 0; ni < 4; ++ni)                         \
        acc[mi][ni] = __builtin_amdgcn_mfma_f32_16x16x32_bf16(af[mi], bfr[ni], acc[mi][ni], 0, 0, 0); }

    // prologue: stage step0 (Ahi,Bhi @0) -> buf0, step1 (Ahi,Blo @0) -> buf1
    ISSUE(0, Ahi, Bhi, 0);
    ISSUE(1, Ahi, Blo, 0);

    for (int k0 = 0; k0 < INF; k0 += 32) {
        const bool notlast = (k0 < INF - 32);
        // step p0: compute buf0 (hi*hi @k0); stage buf2 <- (Alo,Bhi @k0)
        WAIT4; BAR;
        ISSUE(2, Alo, Bhi, k0);
        COMPUTE(0);
        // step p1: compute buf1 (hi*lo @k0); stage buf0 <- (Ahi,Bhi @k0+32)
        WAIT4; BAR;
        if (notlast) ISSUE(0, Ahi, Bhi, k0 + 32);
        COMPUTE(1);
        // step p2: compute buf2 (lo*hi @k0); stage buf1 <- (Ahi,Blo @k0+32)
        if (notlast) { WAIT4; } else { WAIT0; }
        BAR;
        if (notlast) ISSUE(1, Ahi, Blo, k0 + 32);
        COMPUTE(2);
    }

    // epilogue: C/D layout col=lane&15, row=(lane>>4)*4+reg
    int ccol = bcol + wc * 64 + (lane & 15);
    int crow = brow + wr * 64 + (lane >> 4) * 4;
    float bv[4];
#pragma unroll
    for (int ni = 0; ni < 4; ++ni) bv[ni] = bias[ccol + ni * 16];
#pragma unroll
    for (int mi = 0; mi < 4; ++mi) {
#pragma unroll
        for (int j = 0; j < 4; ++j) {
            float* cp = C + (size_t)(crow + mi * 16 + j) * OUTF + ccol;
#pragma unroll
            for (int ni = 0; ni < 4; ++ni)
                cp[ni * 16] = acc[mi][ni][j] + bv[ni];
        }
    }
}

extern "C" void kernel_launch(void* const* d_in, const int* in_sizes, int n_in,
                              void* d_out, int out_size, void* d_ws, size_t ws_size,
                              hipStream_t stream) {
    const float* x    = (const float*)d_in[0];
    const int*   wq   = (const int*)d_in[1];
    const float* wn   = (const float*)d_in[2];
    const float* bias = (const float*)d_in[3];
    float* out = (float*)d_out;

    unsigned short* Ahi = (unsigned short*)d_ws;
    unsigned short* Alo = Ahi + (size_t)TOKENS * INF;
    unsigned short* Bhi = Alo + (size_t)TOKENS * INF;
    unsigned short* Blo = Bhi + (size_t)OUTF * INF;

    prep_x_kernel<<<(TOKENS * INF / 4) / 256, 256, 0, stream>>>(
        (const float4*)x, (ushort4*)Ahi, (ushort4*)Alo);
    prep_w_kernel<<<(OUTF * PACKED / 4) / 256, 256, 0, stream>>>(
        (const int4*)wq, wn, (ushort4*)Bhi, (ushort4*)Blo);
    gemm3_kernel<<<2048, 256, 0, stream>>>(Ahi, Alo, Bhi, Blo, bias, out);
}

// Round 6
// 875.644 us; speedup vs baseline: 1.5569x; 1.5556x over previous
//
#include <hip/hip_runtime.h>
#include <stdint.h>

// Linear4Bit: out[8192,4096] = x @ W^T + bias, W = dequant(int4, group-16 fp32 scales)
// bf16 3-term split GEMM (hh + hl + lh), 256x256 tile, BK=32, 8 waves (2Mx4N),
// 6 phases/k0 of 16 MFMA, dbuf 128KB LDS, combined hi|lo tiles (4 loads/k0 not 6),
// slot^=(row&7) swizzle (pre-swizzled global source, linear LDS dest), setprio.

#define TOKENS 8192
#define INF    4096
#define OUTF   4096
#define GROUPS (INF / 16)   // 256
#define PACKED (INF / 2)    // 2048

typedef short bf16x8 __attribute__((ext_vector_type(8)));
typedef float f32x4  __attribute__((ext_vector_type(4)));

__device__ __forceinline__ unsigned short f2bf(float f) {
    uint32_t u = __float_as_uint(f);
    u += 0x7fffu + ((u >> 16) & 1u);
    return (unsigned short)(u >> 16);
}
__device__ __forceinline__ float bf2f(unsigned short h) {
    return __uint_as_float(((uint32_t)h) << 16);
}

// ---------------- prep: x -> (x_hi, x_lo) bf16 ----------------
__global__ __launch_bounds__(256) void prep_x_kernel(
    const float4* __restrict__ x, ushort4* __restrict__ ahi, ushort4* __restrict__ alo) {
    int i = blockIdx.x * 256 + threadIdx.x;
    float4 v = x[i];
    ushort4 h, l;
    h.x = f2bf(v.x); l.x = f2bf(v.x - bf2f(h.x));
    h.y = f2bf(v.y); l.y = f2bf(v.y - bf2f(h.y));
    h.z = f2bf(v.z); l.z = f2bf(v.z - bf2f(h.z));
    h.w = f2bf(v.w); l.w = f2bf(v.w - bf2f(h.w));
    ahi[i] = h; alo[i] = l;
}

// ---------------- prep: dequant W -> (W_hi, W_lo) bf16 ----------------
__device__ __forceinline__ float dq(int q, float s) {
    return s * (2.0f * ((float)q / 15.0f) - 1.0f);
}

__global__ __launch_bounds__(256) void prep_w_kernel(
    const int4* __restrict__ wq, const float* __restrict__ wn,
    ushort4* __restrict__ bhi, ushort4* __restrict__ blo) {
    int i = blockIdx.x * 256 + threadIdx.x;
    int n  = i / (PACKED / 4);
    int p4 = i - n * (PACKED / 4);
    float s = wn[n * GROUPS + (p4 >> 1)];
    int4 v = wq[i];
    float w[8];
    w[0] = dq(v.x & 15, s);        w[1] = dq((v.x >> 4) & 15, s);
    w[2] = dq(v.y & 15, s);        w[3] = dq((v.y >> 4) & 15, s);
    w[4] = dq(v.z & 15, s);        w[5] = dq((v.z >> 4) & 15, s);
    w[6] = dq(v.w & 15, s);        w[7] = dq((v.w >> 4) & 15, s);
    ushort4 h0, h1, l0, l1;
    h0.x = f2bf(w[0]); l0.x = f2bf(w[0] - bf2f(h0.x));
    h0.y = f2bf(w[1]); l0.y = f2bf(w[1] - bf2f(h0.y));
    h0.z = f2bf(w[2]); l0.z = f2bf(w[2] - bf2f(h0.z));
    h0.w = f2bf(w[3]); l0.w = f2bf(w[3] - bf2f(h0.w));
    h1.x = f2bf(w[4]); l1.x = f2bf(w[4] - bf2f(h1.x));
    h1.y = f2bf(w[5]); l1.y = f2bf(w[5] - bf2f(h1.y));
    h1.z = f2bf(w[6]); l1.z = f2bf(w[6] - bf2f(h1.z));
    h1.w = f2bf(w[7]); l1.w = f2bf(w[7] - bf2f(h1.w));
    bhi[i * 2] = h0; bhi[i * 2 + 1] = h1;
    blo[i * 2] = l0; blo[i * 2 + 1] = l1;
}

// ---------------- 256x256 3-term GEMM ----------------
#define GLDS(g, l) __builtin_amdgcn_global_load_lds(                         \
    (const __attribute__((address_space(1))) void*)(g),                      \
    (__attribute__((address_space(3))) void*)(l), 16, 0, 0)

#define WAITV0 { asm volatile("s_waitcnt vmcnt(0)" ::: "memory"); \
                 __builtin_amdgcn_sched_barrier(0); }
#define BARX   { asm volatile("s_barrier" ::: "memory"); \
                 __builtin_amdgcn_sched_barrier(0); }
#define PRIO1  __builtin_amdgcn_s_setprio(1);
#define PRIO0  __builtin_amdgcn_s_setprio(0);

#define LD(off) (*(const bf16x8*)&lds[(off)])

__global__ __launch_bounds__(512, 2) void gemm3_kernel(
    const unsigned short* __restrict__ Ahi, const unsigned short* __restrict__ Alo,
    const unsigned short* __restrict__ Bhi, const unsigned short* __restrict__ Blo,
    const float* __restrict__ bias, float* __restrict__ C) {
    // 2 buffers x (A[256 rows][64 bf16: slots0-3=hi,4-7=lo] + B same) = 128 KB
    __shared__ unsigned short lds[65536];

    const int NB_N = OUTF / 256;                    // 16
    const int nwg  = (TOKENS / 256) * NB_N;         // 512 (%8==0 -> bijective)
    int bid = blockIdx.x;
    int swz = (bid & 7) * (nwg >> 3) + (bid >> 3);  // XCD swizzle
    int tm = swz / NB_N, tn = swz % NB_N;
    int brow = tm * 256, bcol = tn * 256;

    int tid = threadIdx.x;
    int lane = tid & 63, wave = tid >> 6;
    int wm = wave >> 2, wn = wave & 3;              // wave owns 128x64 of C

    // ---- staging mapping: 512 thr x 16B = 8KB = 64 rows x 128B per G-load ----
    int rloc = tid >> 3;                            // 0..63 row within 64-row chunk
    int lin_slot = tid & 7;                         // linear 16B slot in LDS row
    int sslot = lin_slot ^ (rloc & 7);              // pre-swizzled source slot
    const unsigned short* pA = (sslot < 4) ? Ahi : Alo;
    const unsigned short* pB = (sslot < 4) ? Bhi : Blo;
    const unsigned short* srcA = pA + (size_t)(brow + rloc) * INF + (sslot & 3) * 8;
    const unsigned short* srcB = pB + (size_t)(bcol + rloc) * INF + (sslot & 3) * 8;
    const size_t rstep = (size_t)64 * INF;

#define STAGE_A(p, kk, rb) GLDS(srcA + (kk) + (rb) * rstep, \
                                lds + (p) * 32768 + (rb) * 4096 + tid * 8)
#define STAGE_B(p, kk, rb) GLDS(srcB + (kk) + (rb) * rstep, \
                                lds + (p) * 32768 + 16384 + (rb) * 4096 + tid * 8)

    // ---- fragment read bases (swizzled): row*64 + (slot^(row&7))*8 ushorts ----
    int l15 = lane & 15, l7 = lane & 7, kq = lane >> 4;   // kq = 16B col group 0..3
    int sH = (kq ^ l7) * 8;                               // hi slot offset
    int sL = sH ^ 32;                                     // lo slot = hi slot ^ 4
    int aBaseH = (wm * 128 + l15) * 64 + sH;
    int aBaseL = (wm * 128 + l15) * 64 + sL;
    int bBaseH = 16384 + (wn * 64 + l15) * 64 + sH;
    int bBaseL = 16384 + (wn * 64 + l15) * 64 + sL;

    f32x4 acc[8][4] = {};

    // prologue: stage k0=0 into buf 0
#pragma unroll
    for (int rb = 0; rb < 4; ++rb) STAGE_A(0, 0, rb);
#pragma unroll
    for (int rb = 0; rb < 4; ++rb) STAGE_B(0, 0, rb);

    for (int ki = 0; ki < 128; ++ki) {
        const int p = ki & 1, q = p ^ 1;
        const int pb = p * 32768;
        const int kn = ki * 32 + 32;
        const bool more = (ki < 127);

        WAITV0; BARX;   // buf p ready, buf q free (its readers done last iter)

        bf16x8 ah[4], al[4], bh[4], bl[4];
        // ---- P0: hh, mhalf0 ----
#pragma unroll
        for (int i = 0; i < 4; ++i) ah[i] = LD(pb + aBaseH + i * 1024);
#pragma unroll
        for (int n = 0; n < 4; ++n) bh[n] = LD(pb + bBaseH + n * 1024);
        if (more) { STAGE_A(q, kn, 0); STAGE_A(q, kn, 2); }
        PRIO1;
#pragma unroll
        for (int i = 0; i < 4; ++i)
#pragma unroll
            for (int n = 0; n < 4; ++n)
                acc[i][n] = __builtin_amdgcn_mfma_f32_16x16x32_bf16(ah[i], bh[n], acc[i][n], 0, 0, 0);
        PRIO0; BARX;
        // ---- P1: hl, mhalf0 ----
#pragma unroll
        for (int n = 0; n < 4; ++n) bl[n] = LD(pb + bBaseL + n * 1024);
        if (more) { STAGE_A(q, kn, 1); STAGE_A(q, kn, 3); }
        PRIO1;
#pragma unroll
        for (int i = 0; i < 4; ++i)
#pragma unroll
            for (int n = 0; n < 4; ++n)
                acc[i][n] = __builtin_amdgcn_mfma_f32_16x16x32_bf16(ah[i], bl[n], acc[i][n], 0, 0, 0);
        PRIO0; BARX;
        // ---- P2: lh, mhalf0 ----
#pragma unroll
        for (int i = 0; i < 4; ++i) al[i] = LD(pb + aBaseL + i * 1024);
        if (more) { STAGE_B(q, kn, 0); STAGE_B(q, kn, 1); }
        PRIO1;
#pragma unroll
        for (int i = 0; i < 4; ++i)
#pragma unroll
            for (int n = 0; n < 4; ++n)
                acc[i][n] = __builtin_amdgcn_mfma_f32_16x16x32_bf16(al[i], bh[n], acc[i][n], 0, 0, 0);
        PRIO0; BARX;
        // ---- P3: hh, mhalf1 ----
#pragma unroll
        for (int i = 0; i < 4; ++i) ah[i] = LD(pb + aBaseH + 4096 + i * 1024);
        if (more) { STAGE_B(q, kn, 2); STAGE_B(q, kn, 3); }
        PRIO1;
#pragma unroll
        for (int i = 0; i < 4; ++i)
#pragma unroll
            for (int n = 0; n < 4; ++n)
                acc[4 + i][n] = __builtin_amdgcn_mfma_f32_16x16x32_bf16(ah[i], bh[n], acc[4 + i][n], 0, 0, 0);
        PRIO0; BARX;
        // ---- P4: hl, mhalf1 (no reads, no stage) ----
        PRIO1;
#pragma unroll
        for (int i = 0; i < 4; ++i)
#pragma unroll
            for (int n = 0; n < 4; ++n)
                acc[4 + i][n] = __builtin_amdgcn_mfma_f32_16x16x32_bf16(ah[i], bl[n], acc[4 + i][n], 0, 0, 0);
        PRIO0; BARX;
        // ---- P5: lh, mhalf1 ----
#pragma unroll
        for (int i = 0; i < 4; ++i) al[i] = LD(pb + aBaseL + 4096 + i * 1024);
        PRIO1;
#pragma unroll
        for (int i = 0; i < 4; ++i)
#pragma unroll
            for (int n = 0; n < 4; ++n)
                acc[4 + i][n] = __builtin_amdgcn_mfma_f32_16x16x32_bf16(al[i], bh[n], acc[4 + i][n], 0, 0, 0);
        PRIO0;
        // boundary barrier = next iteration's top
    }

    // epilogue: C/D col=lane&15, row=(lane>>4)*4+j
    int ccol = bcol + wn * 64 + l15;
    int crow = brow + wm * 128 + (lane >> 4) * 4;
    float bv[4];
#pragma unroll
    for (int n = 0; n < 4; ++n) bv[n] = bias[ccol + n * 16];
#pragma unroll
    for (int mi = 0; mi < 8; ++mi) {
#pragma unroll
        for (int j = 0; j < 4; ++j) {
            float* cp = C + (size_t)(crow + mi * 16 + j) * OUTF + ccol;
#pragma unroll
            for (int n = 0; n < 4; ++n)
                cp[n * 16] = acc[mi][n][j] + bv[n];
        }
    }
}

extern "C" void kernel_launch(void* const* d_in, const int* in_sizes, int n_in,
                              void* d_out, int out_size, void* d_ws, size_t ws_size,
                              hipStream_t stream) {
    const float* x    = (const float*)d_in[0];
    const int*   wq   = (const int*)d_in[1];
    const float* wn   = (const float*)d_in[2];
    const float* bias = (const float*)d_in[3];
    float* out = (float*)d_out;

    unsigned short* Ahi = (unsigned short*)d_ws;
    unsigned short* Alo = Ahi + (size_t)TOKENS * INF;
    unsigned short* Bhi = Alo + (size_t)TOKENS * INF;
    unsigned short* Blo = Bhi + (size_t)OUTF * INF;

    prep_x_kernel<<<(TOKENS * INF / 4) / 256, 256, 0, stream>>>(
        (const float4*)x, (ushort4*)Ahi, (ushort4*)Alo);
    prep_w_kernel<<<(OUTF * PACKED / 4) / 256, 256, 0, stream>>>(
        (const int4*)wq, wn, (ushort4*)Bhi, (ushort4*)Blo);
    gemm3_kernel<<<512, 512, 0, stream>>>(Ahi, Alo, Bhi, Blo, bias, out);
}

// Round 7
// 694.714 us; speedup vs baseline: 1.9624x; 1.2604x over previous
//
#include <hip/hip_runtime.h>
#include <stdint.h>

// Linear4Bit: out[8192,4096] = x @ W^T + bias, W = dequant(int4, group-16 fp32 scales)
// 2-term split GEMM: x = x_hi + x_lo (bf16 each), W = bf16(W) single plane.
//   y ~= x_hi@W + x_lo@W   (dropped W-rounding term ~0.1-0.2 absmax)
// 256x256 tile, BK=32, 8 waves (2Mx4N), ring-3 LDS (3 x 48KB = 144KB),
// counted vmcnt(6) (never 0 in loop), ONE barrier/iter, setprio, 4-slot XOR swizzle.

#define TOKENS 8192
#define INF    4096
#define OUTF   4096
#define GROUPS (INF / 16)   // 256
#define PACKED (INF / 2)    // 2048

typedef short bf16x8 __attribute__((ext_vector_type(8)));
typedef float f32x4  __attribute__((ext_vector_type(4)));
typedef unsigned short ushort8v __attribute__((ext_vector_type(8)));

__device__ __forceinline__ unsigned short f2bf(float f) {
    uint32_t u = __float_as_uint(f);
    u += 0x7fffu + ((u >> 16) & 1u);
    return (unsigned short)(u >> 16);
}
__device__ __forceinline__ float bf2f(unsigned short h) {
    return __uint_as_float(((uint32_t)h) << 16);
}

// ---------------- prep: x -> (x_hi, x_lo) bf16 ----------------
__global__ __launch_bounds__(256) void prep_x_kernel(
    const float4* __restrict__ x, ushort4* __restrict__ ahi, ushort4* __restrict__ alo) {
    int i = blockIdx.x * 256 + threadIdx.x;
    float4 v = x[i];
    ushort4 h, l;
    h.x = f2bf(v.x); l.x = f2bf(v.x - bf2f(h.x));
    h.y = f2bf(v.y); l.y = f2bf(v.y - bf2f(h.y));
    h.z = f2bf(v.z); l.z = f2bf(v.z - bf2f(h.z));
    h.w = f2bf(v.w); l.w = f2bf(v.w - bf2f(h.w));
    ahi[i] = h; alo[i] = l;
}

// ---------------- prep: dequant W -> bf16 single plane ----------------
__device__ __forceinline__ float dq(int q, float s) {
    return s * (2.0f * ((float)q / 15.0f) - 1.0f);
}

__global__ __launch_bounds__(256) void prep_w_kernel(
    const int4* __restrict__ wq, const float* __restrict__ wn,
    ushort8v* __restrict__ bw) {
    int i = blockIdx.x * 256 + threadIdx.x;        // one int4 = 8 codes
    int n  = i / (PACKED / 4);
    int p4 = i - n * (PACKED / 4);
    float s = wn[n * GROUPS + (p4 >> 1)];
    int4 v = wq[i];
    ushort8v o;
    o[0] = f2bf(dq(v.x & 15, s));  o[1] = f2bf(dq((v.x >> 4) & 15, s));
    o[2] = f2bf(dq(v.y & 15, s));  o[3] = f2bf(dq((v.y >> 4) & 15, s));
    o[4] = f2bf(dq(v.z & 15, s));  o[5] = f2bf(dq((v.z >> 4) & 15, s));
    o[6] = f2bf(dq(v.w & 15, s));  o[7] = f2bf(dq((v.w >> 4) & 15, s));
    bw[i] = o;                                     // 16B store
}

// ---------------- 2-term ring-3 GEMM ----------------
#define GLDS(g, l) __builtin_amdgcn_global_load_lds(                         \
    (const __attribute__((address_space(1))) void*)(g),                      \
    (__attribute__((address_space(3))) void*)(l), 16, 0, 0)

#define WAITV6 { asm volatile("s_waitcnt vmcnt(6)" ::: "memory"); \
                 __builtin_amdgcn_sched_barrier(0); }
#define WAITV0 { asm volatile("s_waitcnt vmcnt(0)" ::: "memory"); \
                 __builtin_amdgcn_sched_barrier(0); }
#define BARX   { asm volatile("s_barrier" ::: "memory"); \
                 __builtin_amdgcn_sched_barrier(0); }
#define PRIO1  __builtin_amdgcn_s_setprio(1);
#define PRIO0  __builtin_amdgcn_s_setprio(0);

#define LD(off) (*(const bf16x8*)&lds[(off)])

// buffer layout (ushort units, 24576 per buffer = 48KB):
//   A_hi [0,8192)  rows 0..255 x 32     A_lo [8192,16384)     B [16384,24576)
#define BUFU 24576

__global__ __launch_bounds__(512, 2) void gemm2_kernel(
    const unsigned short* __restrict__ Ahi, const unsigned short* __restrict__ Alo,
    const unsigned short* __restrict__ Bw,
    const float* __restrict__ bias, float* __restrict__ C) {
    __shared__ unsigned short lds[3 * BUFU];       // 144 KB

    const int NB_N = OUTF / 256;                    // 16
    const int nwg  = (TOKENS / 256) * NB_N;         // 512 (%8==0 -> bijective)
    int bid = blockIdx.x;
    int swz = (bid & 7) * (nwg >> 3) + (bid >> 3);  // XCD swizzle
    int tm = swz / NB_N, tn = swz % NB_N;
    int brow = tm * 256, bcol = tn * 256;

    int tid = threadIdx.x;
    int lane = tid & 63, wave = tid >> 6;
    int wm = wave >> 2, wn = wave & 3;              // wave owns 128x64 of C

    // ---- staging: 512 thr x 16B = 8KB = 128 rows x 64B per G-load pass ----
    int rloc = tid >> 2;                            // 0..127 local row (pass adds 128)
    int sslot = (tid & 3) ^ ((tid >> 3) & 3);       // pre-swizzled source 16B slot
    const unsigned short* srcAh = Ahi + (size_t)(brow + rloc) * INF + sslot * 8;
    const unsigned short* srcAl = Alo + (size_t)(brow + rloc) * INF + sslot * 8;
    const unsigned short* srcB  = Bw  + (size_t)(bcol + rloc) * INF + sslot * 8;
    const size_t half = (size_t)128 * INF;          // rows +128

#define STAGE(bu, kk) {                                            \
    GLDS(srcAh + (kk),        lds + (bu)         + tid * 8);       \
    GLDS(srcAh + (kk) + half, lds + (bu) +  4096 + tid * 8);       \
    GLDS(srcAl + (kk),        lds + (bu) +  8192 + tid * 8);       \
    GLDS(srcAl + (kk) + half, lds + (bu) + 12288 + tid * 8);       \
    GLDS(srcB  + (kk),        lds + (bu) + 16384 + tid * 8);       \
    GLDS(srcB  + (kk) + half, lds + (bu) + 20480 + tid * 8); }

    // ---- fragment read bases (swizzled): [row][32], col16B = kq ^ ((row>>1)&3) ----
    int l15 = lane & 15, kq = lane >> 4;
    int x8 = (kq ^ ((l15 >> 1) & 3)) * 8;           // wave-row-base terms are %4==0
    int aRow = (wm * 128 + l15) * 32 + x8;          // + mi*512
    int bRow = 16384 + (wn * 64 + l15) * 32 + x8;   // + ni*512

    f32x4 acc[8][4] = {};

    // prologue: stage tiles 0,1 into bufs 0,1 (12 loads outstanding)
    STAGE(0, 0);
    STAGE(BUFU, 32);

    for (int ki = 0; ki < 128; ++ki) {
        const int bb = (ki % 3) * BUFU;
        if (ki == 127) { WAITV0 } else { WAITV6 }   // own stage(ki) landed
        BARX;                                       // all waves: stage(ki) landed,
                                                    // compute(ki-1) done everywhere
        if (ki < 126) {
            const int sb = ((ki + 2) % 3) * BUFU;
            STAGE(sb, (ki + 2) * 32);               // safe: its readers pre-barrier
        }

        bf16x8 bw[4], ah[8], al[8];
#pragma unroll
        for (int n = 0; n < 4; ++n) bw[n] = LD(bb + bRow + n * 512);
#pragma unroll
        for (int m = 0; m < 8; ++m) ah[m] = LD(bb + aRow + m * 512);
        PRIO1;
#pragma unroll
        for (int m = 0; m < 8; ++m)
#pragma unroll
            for (int n = 0; n < 4; ++n)
                acc[m][n] = __builtin_amdgcn_mfma_f32_16x16x32_bf16(ah[m], bw[n], acc[m][n], 0, 0, 0);
        PRIO0;
#pragma unroll
        for (int m = 0; m < 8; ++m) al[m] = LD(bb + 8192 + aRow + m * 512);
        PRIO1;
#pragma unroll
        for (int m = 0; m < 8; ++m)
#pragma unroll
            for (int n = 0; n < 4; ++n)
                acc[m][n] = __builtin_amdgcn_mfma_f32_16x16x32_bf16(al[m], bw[n], acc[m][n], 0, 0, 0);
        PRIO0;
    }

    // epilogue: C/D col=lane&15, row=(lane>>4)*4+j
    int ccol = bcol + wn * 64 + l15;
    int crow = brow + wm * 128 + (lane >> 4) * 4;
    float bv[4];
#pragma unroll
    for (int n = 0; n < 4; ++n) bv[n] = bias[ccol + n * 16];
#pragma unroll
    for (int mi = 0; mi < 8; ++mi) {
#pragma unroll
        for (int j = 0; j < 4; ++j) {
            float* cp = C + (size_t)(crow + mi * 16 + j) * OUTF + ccol;
#pragma unroll
            for (int n = 0; n < 4; ++n)
                cp[n * 16] = acc[mi][n][j] + bv[n];
        }
    }
}

extern "C" void kernel_launch(void* const* d_in, const int* in_sizes, int n_in,
                              void* d_out, int out_size, void* d_ws, size_t ws_size,
                              hipStream_t stream) {
    const float* x    = (const float*)d_in[0];
    const int*   wq   = (const int*)d_in[1];
    const float* wn   = (const float*)d_in[2];
    const float* bias = (const float*)d_in[3];
    float* out = (float*)d_out;

    // workspace: Ahi 64MB | Alo 64MB | Bw 32MB  (160 MB)
    unsigned short* Ahi = (unsigned short*)d_ws;
    unsigned short* Alo = Ahi + (size_t)TOKENS * INF;
    unsigned short* Bw  = Alo + (size_t)TOKENS * INF;

    prep_x_kernel<<<(TOKENS * INF / 4) / 256, 256, 0, stream>>>(
        (const float4*)x, (ushort4*)Ahi, (ushort4*)Alo);
    prep_w_kernel<<<(OUTF * PACKED / 4) / 256, 256, 0, stream>>>(
        (const int4*)wq, wn, (ushort8v*)Bw);
    gemm2_kernel<<<512, 512, 0, stream>>>(Ahi, Alo, Bw, bias, out);
}